// Round 6
// baseline (729.949 us; speedup 1.0000x reference)
//
#include <hip/hip_runtime.h>
#include <hip/hip_bf16.h>
#include <stdint.h>

// ---------------- problem constants ----------------
#define N_TOK 8192
#define DIM   1024
#define FF    4096
#define NEXP  8
#define MAXT1 72     // 256-row tiles: sum ceil(ce/256) <= 64+8
#define MAXT2 136    // 128-row tiles: sum ceil(ce/128) <= 128+8

// ---------------- workspace layout (bytes) ----------------
#define OFF_COUNTS 0ull
#define OFF_NT     64ull              // [0]=ntiles256 [1]=ntiles128
#define OFF_T256   4096ull            // 72*16
#define OFF_T128   8192ull            // 136*16
#define OFF_IDX    16384ull           // 8*8192*4
#define OFF_GATE   278528ull
#define OFF_XB     1048576ull         // 8192*1024*2
#define OFF_H      17825792ull        // 18432*4096*2 = 150,994,944
#define OFF_WB     168820736ull       // 8*4096*1024*2 (w1b, then w2b aliased)
#define NEED       235929600ull

typedef __attribute__((ext_vector_type(8))) short s16x8;   // 8 bf16 MFMA frag
typedef __attribute__((ext_vector_type(4))) float f32x4;   // MFMA accum

__device__ __forceinline__ unsigned short f2bf(float f) {
  union { float f; unsigned int u; } v; v.f = f;
  unsigned int u = v.u;
  unsigned int r = (u + 0x7FFFu + ((u >> 16) & 1u)) >> 16;  // RNE
  return (unsigned short)r;
}

// gelu: 0.5*x*(1+erf(x/sqrt2)), erf via A&S 7.1.26 (|err|<1.5e-7)
__device__ __forceinline__ float gelu_f(float x) {
  float s = x * 0.70710678118654752f;
  float a = fabsf(s);
  float t = 1.0f / fmaf(0.3275911f, a, 1.0f);
  float p = t * fmaf(t, fmaf(t, fmaf(t, fmaf(t, 1.061405429f, -1.453152027f),
                                     1.421413741f), -0.284496736f), 0.254829592f);
  float e = __expf(-a * a);
  float erf_a = 1.0f - p * e;
  float erf_s = (s >= 0.0f) ? erf_a : -erf_a;
  return 0.5f * x * (1.0f + erf_s);
}

// async global -> LDS, 16B per lane (dest = wave-uniform base + lane*16)
__device__ __forceinline__ void load_lds16(const void* g, void* l) {
  __builtin_amdgcn_global_load_lds(
      (const __attribute__((address_space(1))) unsigned int*)g,
      (__attribute__((address_space(3))) unsigned int*)l, 16, 0, 0);
}

// ---------------- f32 -> bf16 bulk convert (weights) ----------------
__global__ __launch_bounds__(256) void cvt_f32_bf16(const float4* __restrict__ in,
                                                    ushort4* __restrict__ out, int n4) {
  int i = blockIdx.x * 256 + threadIdx.x;
  int stride = gridDim.x * 256;
  for (; i < n4; i += stride) {
    float4 f = in[i];
    ushort4 u;
    u.x = f2bf(f.x); u.y = f2bf(f.y); u.z = f2bf(f.z); u.w = f2bf(f.w);
    out[i] = u;
  }
}

// ---------------- router: 1 wave per token; also emits xb (bf16 copy of x) ----
__global__ __launch_bounds__(256) void router_kernel(
    const float* __restrict__ x, const float* __restrict__ rw,
    int* __restrict__ counts, int* __restrict__ idx_list, float* __restrict__ gate_list,
    unsigned short* __restrict__ xb) {
  int wid = threadIdx.x >> 6;
  int lane = threadIdx.x & 63;
  int token = blockIdx.x * 4 + wid;

  const float4* xr = (const float4*)(x + (size_t)token * DIM);
  ushort4* xw = (ushort4*)(xb + (size_t)token * DIM);
  float p[NEXP];
#pragma unroll
  for (int e = 0; e < NEXP; ++e) p[e] = 0.f;
#pragma unroll
  for (int c = 0; c < 4; ++c) {
    float4 xv = xr[c * 64 + lane];
    ushort4 u;
    u.x = f2bf(xv.x); u.y = f2bf(xv.y); u.z = f2bf(xv.z); u.w = f2bf(xv.w);
    xw[c * 64 + lane] = u;
#pragma unroll
    for (int e = 0; e < NEXP; ++e) {
      float4 wv = ((const float4*)(rw + (size_t)e * DIM))[c * 64 + lane];
      p[e] += xv.x * wv.x + xv.y * wv.y + xv.z * wv.z + xv.w * wv.w;
    }
  }
#pragma unroll
  for (int e = 0; e < NEXP; ++e) {
    float v = p[e];
#pragma unroll
    for (int off = 32; off > 0; off >>= 1) v += __shfl_xor(v, off, 64);
    p[e] = v;
  }
  if (lane == 0) {
    int e0 = 0; float v0 = p[0];
#pragma unroll
    for (int e = 1; e < NEXP; ++e) if (p[e] > v0) { v0 = p[e]; e0 = e; }
    int e1 = (e0 == 0) ? 1 : 0; float v1 = -3.4e38f;
#pragma unroll
    for (int e = 0; e < NEXP; ++e) if (e != e0 && p[e] > v1) { v1 = p[e]; e1 = e; }
    float ex = __expf(v1 - v0);
    float g0 = 1.0f / (1.0f + ex);
    float g1 = ex / (1.0f + ex);
    int p0 = atomicAdd(&counts[e0], 1);
    idx_list[e0 * N_TOK + p0] = token;
    gate_list[e0 * N_TOK + p0] = g0;
    int p1 = atomicAdd(&counts[e1], 1);
    idx_list[e1 * N_TOK + p1] = token;
    gate_list[e1 * N_TOK + p1] = g1;
  }
}

// ---------------- schedule: counts -> 256-row and 128-row tile tables --------
__global__ void schedule_kernel(const int* __restrict__ counts, int4* __restrict__ t256,
                                int4* __restrict__ t128, int* __restrict__ nt) {
  if (threadIdx.x == 0 && blockIdx.x == 0) {
    int a = 0, b = 0, gb = 0;
    for (int e = 0; e < NEXP; ++e) {
      int c = counts[e];
      int n1 = (c + 255) >> 8, n2 = (c + 127) >> 7;
      for (int i = 0; i < n1; ++i) t256[a++] = make_int4(e, i << 8, gb + (i << 8), 0);
      for (int i = 0; i < n2; ++i) t128[b++] = make_int4(e, i << 7, gb + (i << 7), 0);
      gb += n1 << 8;
    }
    nt[0] = a; nt[1] = b;
  }
}

// ---------------- grouped GEMM: BMxBN, BK=32, 4-slot ring, depth-3, ---------
// ---------------- m201-style double-barrier phase discipline ----------------
// Per K-tile t, TWO phases, each {ds_read quadrant; stage-issue(t+3); s_barrier;
// (lgkm by compiler) setprio(1) MFMA cluster setprio(0); s_barrier}. Tile
// boundary: counted s_waitcnt vmcnt(8/4/0 ladder, never 0 mid-loop) BEFORE the
// trailing barrier -> tile t+1 fully in LDS for all waves after it; tiles
// t+2,t+3 stay in flight. Ring slot (t+3)&3 == (t-1)&3 is free: its A last
// read in ph1(t-1), B in ph0(t-1), both complete before that tile's barriers.
// XCD swizzle (T1): block o -> L=(o&7)*CPX+(o>>3); cx=L%CXW so each XCD owns
// a contiguous ty range; LDS 16B-slot swizzle s^((r>>1)&3) via pre-swizzled
// global source (linear gload_lds dest), same XOR on read (conflict-free, r5).
// EPI==1: H[gbase+r] = gelu(A_gathered @ W^T) (bf16).
// EPI==2: atomicAdd(Out[token], gate * (H @ W^T)).
template <int BM, int BN, int WRN, int WCN, int KDIM, int EPI, int CXW, int CPX>
__global__ __launch_bounds__(WRN * WCN * 64, 2) void moe_deep(
    const unsigned short* __restrict__ Abase, const unsigned short* __restrict__ Bb,
    unsigned short* __restrict__ Hout, float* __restrict__ Out,
    const int* __restrict__ idx_list, const float* __restrict__ gate_list,
    const int* __restrict__ counts, const int4* __restrict__ table,
    const int* __restrict__ n_tiles) {
  constexpr int THREADS = WRN * WCN * 64;
  constexpr int ASLOT = BM * 64;   // bytes per ring slot
  constexpr int BSLOT = BN * 64;
  constexpr int MFR = BM / WRN / 16;
  constexpr int HM = MFR / 2;
  static_assert(BM * 64 == 2 * THREADS * 16 && BN * 64 == 2 * THREADS * 16, "stage geometry");

  const int o = blockIdx.x;
  const int L = (o & 7) * CPX + (o >> 3);
  const int cx = L % CXW, ty = L / CXW;
  if (ty >= *n_tiles) return;
  int4 te = table[ty];
  const int e = te.x, row_start = te.y, gbase = te.z;
  const int ce = counts[e];
  const int tid = threadIdx.x;
  const int wid = tid >> 6, lane = tid & 63;
  const int colT = cx * BN;

  extern __shared__ char smem[];
  char* Als = smem;                  // [4][ASLOT]
  char* Bls = smem + 4 * ASLOT;      // [4][BSLOT]

  // staging: thread -> rows {sr, THREADS/4+sr}, phys 16B-slot tid&3; source
  // pre-swizzled so phys slot holds logical slot (tid&3)^((row>>1)&3).
  const int sr = tid >> 2;
  const int scol = ((tid & 3) ^ ((sr >> 1) & 3)) * 8;
  size_t aoff[2], boff[2];
#pragma unroll
  for (int j = 0; j < 2; ++j) {
    int r = j * (THREADS / 4) + sr;
    if constexpr (EPI == 1) {
      int rl = row_start + r; if (rl >= ce) rl = ce - 1;   // clamp padded rows
      int tok = idx_list[e * N_TOK + rl];
      aoff[j] = ((size_t)tok * KDIM + scol) * 2;
    } else {
      aoff[j] = ((size_t)(gbase + r) * KDIM + scol) * 2;
    }
    boff[j] = ((size_t)e * FF * DIM + (size_t)(colT + r) * KDIM + scol) * 2;
  }
  const char* Ag = (const char*)Abase;
  const char* Bg = (const char*)Bb;

  auto stageA = [&](int t2) {
    char* dst = Als + (size_t)(t2 & 3) * ASLOT + tid * 16;
    size_t ko = (size_t)t2 * 64;
    load_lds16(Ag + aoff[0] + ko, dst);
    load_lds16(Ag + aoff[1] + ko, dst + THREADS * 16);
  };
  auto stageB = [&](int t2) {
    char* dst = Bls + (size_t)(t2 & 3) * BSLOT + tid * 16;
    size_t ko = (size_t)t2 * 64;
    load_lds16(Bg + boff[0] + ko, dst);
    load_lds16(Bg + boff[1] + ko, dst + THREADS * 16);
  };

  // fragment read geometry
  const int wr = wid / WCN, wc = wid % WCN;
  const int rowbase = wr * (BM / WRN), colbase = wc * 64;
  const int r16 = lane & 15, kg = lane >> 4;
  const int so = (kg ^ ((r16 >> 1) & 3)) << 4;
  const int arowoff = (rowbase + r16) * 64 + so;
  const int browoff = (colbase + r16) * 64 + so;

  f32x4 acc[MFR][4] = {};
  const int NT = KDIM / 32;

  // prologue: tiles 0,1,2 (issue order = vmcnt order)
  stageA(0); stageB(0); stageA(1); stageB(1); stageA(2); stageB(2);
  asm volatile("s_waitcnt vmcnt(8)" ::: "memory");   // tile 0 landed
  asm volatile("s_barrier" ::: "memory");

  for (int t = 0; t < NT; ++t) {
    const char* Ap = Als + (size_t)(t & 3) * ASLOT + arowoff;
    const char* Bp = Bls + (size_t)(t & 3) * BSLOT + browoff;
    s16x8 a[HM], b[4];
    // ---- phase 0: B + A-quadrant 0, stage A(t+3), MFMA q0
#pragma unroll
    for (int n = 0; n < 4; ++n) b[n] = *(const s16x8*)(Bp + n * 1024);
#pragma unroll
    for (int m = 0; m < HM; ++m) a[m] = *(const s16x8*)(Ap + m * 1024);
    if (t + 3 < NT) stageA(t + 3);
    asm volatile("s_barrier" ::: "memory");
    __builtin_amdgcn_s_setprio(1);
#pragma unroll
    for (int m = 0; m < HM; ++m)
#pragma unroll
      for (int n = 0; n < 4; ++n)
        acc[m][n] = __builtin_amdgcn_mfma_f32_16x16x32_bf16(a[m], b[n], acc[m][n], 0, 0, 0);
    __builtin_amdgcn_s_setprio(0);
    asm volatile("s_barrier" ::: "memory");
    // ---- phase 1: A-quadrant 1, stage B(t+3), MFMA q1
#pragma unroll
    for (int m = 0; m < HM; ++m) a[m] = *(const s16x8*)(Ap + (HM + m) * 1024);
    if (t + 3 < NT) stageB(t + 3);
    asm volatile("s_barrier" ::: "memory");
    __builtin_amdgcn_s_setprio(1);
#pragma unroll
    for (int m = 0; m < HM; ++m)
#pragma unroll
      for (int n = 0; n < 4; ++n)
        acc[HM + m][n] = __builtin_amdgcn_mfma_f32_16x16x32_bf16(a[m], b[n],
                                                                 acc[HM + m][n], 0, 0, 0);
    __builtin_amdgcn_s_setprio(0);
    // ---- tile boundary: counted wait (tile t+1 ready; t+2,t+3 in flight)
    const int pend = NT - 1 - t;
    if (pend >= 1) {
      if (pend >= 3)      asm volatile("s_waitcnt vmcnt(8)" ::: "memory");
      else if (pend == 2) asm volatile("s_waitcnt vmcnt(4)" ::: "memory");
      else                asm volatile("s_waitcnt vmcnt(0)" ::: "memory");
      asm volatile("s_barrier" ::: "memory");
    }
  }

  // ---- epilogue
  if constexpr (EPI == 1) {
#pragma unroll
    for (int m = 0; m < MFR; ++m) {
      const int row_l = rowbase + m * 16 + kg * 4;
#pragma unroll
      for (int j = 0; j < 4; ++j) {
        size_t hrow = (size_t)(gbase + row_l + j) * FF + colT + colbase;
#pragma unroll
        for (int n = 0; n < 4; ++n)
          Hout[hrow + n * 16 + r16] = f2bf(gelu_f(acc[m][n][j]));
      }
    }
  } else {
#pragma unroll
    for (int m = 0; m < MFR; ++m) {
      const int row_l = rowbase + m * 16 + kg * 4;
#pragma unroll
      for (int j = 0; j < 4; ++j) {
        int r = row_start + row_l + j;
        if (r < ce) {
          int tok = idx_list[e * N_TOK + r];
          float g = gate_list[e * N_TOK + r];
          float* orow = Out + (size_t)tok * DIM + colT + colbase;
#pragma unroll
          for (int n = 0; n < 4; ++n)
            atomicAdd(&orow[n * 16 + r16], acc[m][n][j] * g);
        }
      }
    }
  }
}

// ---------------- launch ----------------
extern "C" void kernel_launch(void* const* d_in, const int* in_sizes, int n_in,
                              void* d_out, int out_size, void* d_ws, size_t ws_size,
                              hipStream_t stream) {
  const float* x  = (const float*)d_in[0];
  const float* rw = (const float*)d_in[1];
  const float* w1 = (const float*)d_in[2];
  const float* w2 = (const float*)d_in[3];
  float* out = (float*)d_out;
  char* ws = (char*)d_ws;
  if (ws_size < NEED) return;

  int*   counts    = (int*)(ws + OFF_COUNTS);
  int*   nt        = (int*)(ws + OFF_NT);
  int4*  t256      = (int4*)(ws + OFF_T256);
  int4*  t128      = (int4*)(ws + OFF_T128);
  int*   idx_list  = (int*)(ws + OFF_IDX);
  float* gate_list = (float*)(ws + OFF_GATE);
  unsigned short* xb = (unsigned short*)(ws + OFF_XB);
  unsigned short* h  = (unsigned short*)(ws + OFF_H);
  unsigned short* wb = (unsigned short*)(ws + OFF_WB);

  hipFuncSetAttribute(reinterpret_cast<const void*>(&moe_deep<256, 256, 2, 4, DIM, 1, 16, 144>),
                      hipFuncAttributeMaxDynamicSharedMemorySize, 131072);
  hipFuncSetAttribute(reinterpret_cast<const void*>(&moe_deep<128, 128, 2, 2, FF, 2, 8, 136>),
                      hipFuncAttributeMaxDynamicSharedMemorySize, 65536);

  hipMemsetAsync(d_out, 0, (size_t)N_TOK * DIM * sizeof(float), stream);
  hipMemsetAsync(ws, 0, 256, stream);  // counts + nt

  router_kernel<<<N_TOK / 4, 256, 0, stream>>>(x, rw, counts, idx_list, gate_list, xb);
  schedule_kernel<<<1, 64, 0, stream>>>(counts, t256, t128, nt);

  // w1 -> bf16, GEMM1, then w2 -> bf16 into the SAME buffer (stream-ordered), GEMM2
  cvt_f32_bf16<<<2048, 256, 0, stream>>>((const float4*)w1, (ushort4*)wb, NEXP * FF * DIM / 4);
  moe_deep<256, 256, 2, 4, DIM, 1, 16, 144><<<16 * MAXT1, 512, 131072, stream>>>(
      xb, wb, h, nullptr, idx_list, gate_list, counts, t256, nt);
  cvt_f32_bf16<<<2048, 256, 0, stream>>>((const float4*)w2, (ushort4*)wb, NEXP * FF * DIM / 4);
  moe_deep<128, 128, 2, 2, FF, 2, 8, 136><<<8 * MAXT2, 256, 65536, stream>>>(
      h, wb, nullptr, out, idx_list, gate_list, counts, t128, nt + 1);
}

// Round 7
// 671.238 us; speedup vs baseline: 1.0875x; 1.0875x over previous
//
#include <hip/hip_runtime.h>
#include <hip/hip_bf16.h>
#include <stdint.h>

// ---------------- problem constants ----------------
#define N_TOK 8192
#define DIM   1024
#define FF    4096
#define NEXP  8
#define MAXT  136    // 128-row tiles: sum ceil(ce/128) <= 128+8

// ---------------- workspace layout (bytes) ----------------
#define OFF_COUNTS 0ull
#define OFF_NT     64ull
#define OFF_T128   8192ull            // 136*16
#define OFF_IDX    16384ull           // 8*8192*4
#define OFF_GATE   278528ull
#define OFF_XB     1048576ull         // 8192*1024*2
#define OFF_H      17825792ull        // 17408*4096*2 fits in 150,994,944
#define OFF_WB     168820736ull       // 8*4096*1024*2 = 67,108,864 (w1b; w2b aliased if small ws)
#define OFF_W2B    235929600ull       // separate w2b when workspace permits
#define NEED       235929600ull
#define NEED2      303038464ull       // OFF_W2B + 67,108,864

typedef __attribute__((ext_vector_type(8))) short s16x8;   // 8 bf16 MFMA frag
typedef __attribute__((ext_vector_type(4))) float f32x4;   // MFMA accum

__device__ __forceinline__ unsigned short f2bf(float f) {
  union { float f; unsigned int u; } v; v.f = f;
  unsigned int u = v.u;
  unsigned int r = (u + 0x7FFFu + ((u >> 16) & 1u)) >> 16;  // RNE
  return (unsigned short)r;
}

// gelu: 0.5*x*(1+erf(x/sqrt2)), erf via A&S 7.1.26 (|err|<1.5e-7)
__device__ __forceinline__ float gelu_f(float x) {
  float s = x * 0.70710678118654752f;
  float a = fabsf(s);
  float t = 1.0f / fmaf(0.3275911f, a, 1.0f);
  float p = t * fmaf(t, fmaf(t, fmaf(t, fmaf(t, 1.061405429f, -1.453152027f),
                                     1.421413741f), -0.284496736f), 0.254829592f);
  float e = __expf(-a * a);
  float erf_a = 1.0f - p * e;
  float erf_s = (s >= 0.0f) ? erf_a : -erf_a;
  return 0.5f * x * (1.0f + erf_s);
}

// async global -> LDS, 16B per lane (dest = wave-uniform base + lane*16)
__device__ __forceinline__ void load_lds16(const void* g, void* l) {
  __builtin_amdgcn_global_load_lds(
      (const __attribute__((address_space(1))) unsigned int*)g,
      (__attribute__((address_space(3))) unsigned int*)l, 16, 0, 0);
}

// ---------------- f32 -> bf16 bulk converts ----------------
__global__ __launch_bounds__(256) void cvt_f32_bf16(const float4* __restrict__ in,
                                                    ushort4* __restrict__ out, int n4) {
  int i = blockIdx.x * 256 + threadIdx.x;
  int stride = gridDim.x * 256;
  for (; i < n4; i += stride) {
    float4 f = in[i];
    ushort4 u;
    u.x = f2bf(f.x); u.y = f2bf(f.y); u.z = f2bf(f.z); u.w = f2bf(f.w);
    out[i] = u;
  }
}

__global__ __launch_bounds__(256) void cvt2_f32_bf16(
    const float4* __restrict__ in1, ushort4* __restrict__ out1,
    const float4* __restrict__ in2, ushort4* __restrict__ out2, int n4) {
  int i = blockIdx.x * 256 + threadIdx.x;
  int stride = gridDim.x * 256;
  for (; i < 2 * n4; i += stride) {
    const float4* src = (i < n4) ? &in1[i] : &in2[i - n4];
    ushort4* dst = (i < n4) ? &out1[i] : &out2[i - n4];
    float4 f = *src;
    ushort4 u;
    u.x = f2bf(f.x); u.y = f2bf(f.y); u.z = f2bf(f.z); u.w = f2bf(f.w);
    *dst = u;
  }
}

// ---------------- router: 1 wave per token; also emits xb (bf16 copy of x) ----
__global__ __launch_bounds__(256) void router_kernel(
    const float* __restrict__ x, const float* __restrict__ rw,
    int* __restrict__ counts, int* __restrict__ idx_list, float* __restrict__ gate_list,
    unsigned short* __restrict__ xb) {
  int wid = threadIdx.x >> 6;
  int lane = threadIdx.x & 63;
  int token = blockIdx.x * 4 + wid;

  const float4* xr = (const float4*)(x + (size_t)token * DIM);
  ushort4* xw = (ushort4*)(xb + (size_t)token * DIM);
  float p[NEXP];
#pragma unroll
  for (int e = 0; e < NEXP; ++e) p[e] = 0.f;
#pragma unroll
  for (int c = 0; c < 4; ++c) {
    float4 xv = xr[c * 64 + lane];
    ushort4 u;
    u.x = f2bf(xv.x); u.y = f2bf(xv.y); u.z = f2bf(xv.z); u.w = f2bf(xv.w);
    xw[c * 64 + lane] = u;
#pragma unroll
    for (int e = 0; e < NEXP; ++e) {
      float4 wv = ((const float4*)(rw + (size_t)e * DIM))[c * 64 + lane];
      p[e] += xv.x * wv.x + xv.y * wv.y + xv.z * wv.z + xv.w * wv.w;
    }
  }
#pragma unroll
  for (int e = 0; e < NEXP; ++e) {
    float v = p[e];
#pragma unroll
    for (int off = 32; off > 0; off >>= 1) v += __shfl_xor(v, off, 64);
    p[e] = v;
  }
  if (lane == 0) {
    int e0 = 0; float v0 = p[0];
#pragma unroll
    for (int e = 1; e < NEXP; ++e) if (p[e] > v0) { v0 = p[e]; e0 = e; }
    int e1 = (e0 == 0) ? 1 : 0; float v1 = -3.4e38f;
#pragma unroll
    for (int e = 0; e < NEXP; ++e) if (e != e0 && p[e] > v1) { v1 = p[e]; e1 = e; }
    float ex = __expf(v1 - v0);
    float g0 = 1.0f / (1.0f + ex);
    float g1 = ex / (1.0f + ex);
    int p0 = atomicAdd(&counts[e0], 1);
    idx_list[e0 * N_TOK + p0] = token;
    gate_list[e0 * N_TOK + p0] = g0;
    int p1 = atomicAdd(&counts[e1], 1);
    idx_list[e1 * N_TOK + p1] = token;
    gate_list[e1 * N_TOK + p1] = g1;
  }
}

// ---------------- schedule: counts -> 128-row tile table (1 wave) ------------
__global__ void schedule_kernel(const int* __restrict__ counts, int4* __restrict__ t128,
                                int* __restrict__ nt) {
  int lane = threadIdx.x;
  int base[NEXP + 1], gb[NEXP];
  int b = 0, g = 0;
#pragma unroll
  for (int e = 0; e < NEXP; ++e) {
    base[e] = b; gb[e] = g;
    int n2 = (counts[e] + 127) >> 7;
    b += n2; g += n2 << 7;
  }
  base[NEXP] = b;
  if (lane == 0) nt[0] = b;
  for (int i = lane; i < b; i += 64) {
    int e = 0;
#pragma unroll
    for (int q = 0; q < NEXP - 1; ++q) if (i >= base[q + 1]) e = q + 1;
    int k = i - base[e];
    t128[i] = make_int4(e, k << 7, gb[e] + (k << 7), 0);
  }
}

// ---------------- grouped GEMM: 128x128, BK=64, 4 waves, single buffer -------
// r1-skeleton (proven best per-structure): {stage; __syncthreads; ds_read+MFMA;
// __syncthreads} per K-tile. Latency hidden by CO-RESIDENT BLOCKS (m114):
// 32 KiB static LDS + __launch_bounds__(256,4) -> 4-5 blocks/CU.
// T1 XCD swizzle: block o -> L=(o&7)*CPX+(o>>3); cx=L%CXW (cx-inner => blocks
// sharing an A-panel are dispatch-adjacent on one XCD; K-phases align -> L2 hits).
// LDS conflict-free: source-pre-swizzled 16B-slot XOR (slot s at row r holds
// global slot s^(r&7)); reads use ((kf*4+kg)^(r16&7)) -> 0 conflicts (r3-verified).
// EPI==1: H[gbase+r] = gelu(A_gathered @ W^T) (bf16).
// EPI==2: atomicAdd(Out[token], gate * (H @ W^T)).
template <int KDIM, int EPI, int CXW, int CPX>
__global__ __launch_bounds__(256, 4) void moe_g(
    const unsigned short* __restrict__ Abase, const unsigned short* __restrict__ Bb,
    unsigned short* __restrict__ Hout, float* __restrict__ Out,
    const int* __restrict__ idx_list, const float* __restrict__ gate_list,
    const int* __restrict__ counts, const int4* __restrict__ table,
    const int* __restrict__ n_tiles) {
  const int o = blockIdx.x;
  const int L = (o & 7) * CPX + (o >> 3);
  const int cx = L % CXW, ty = L / CXW;
  if (ty >= *n_tiles) return;
  int4 te = table[ty];
  const int e = te.x, row_start = te.y, gbase = te.z;
  const int ce = counts[e];
  const int tid = threadIdx.x;
  const int wid = tid >> 6, lane = tid & 63;
  const int colT = cx * 128;

  __shared__ unsigned short Al[128 * 64];
  __shared__ unsigned short Bl[128 * 64];

  // staging: thread -> rows {i*32+sr}, phys 16B-slot tid&7; source pre-swizzled
  const int sr = tid >> 3;
  const int scol = ((tid & 7) ^ (sr & 7)) * 8;
  size_t aoff[4], boff[4];
#pragma unroll
  for (int i = 0; i < 4; ++i) {
    int r = i * 32 + sr;
    if constexpr (EPI == 1) {
      int rl = row_start + r; if (rl >= ce) rl = ce - 1;   // clamp padded rows
      int tok = idx_list[e * N_TOK + rl];
      aoff[i] = ((size_t)tok * KDIM + scol) * 2;
    } else {
      aoff[i] = ((size_t)(gbase + r) * KDIM + scol) * 2;
    }
    boff[i] = ((size_t)e * FF * DIM + (size_t)(colT + r) * KDIM + scol) * 2;
  }
  const char* Ag = (const char*)Abase;
  const char* Bg = (const char*)Bb;
  const int NT = KDIM / 64;

  const int wr = (wid >> 1) * 64, wc = (wid & 1) * 64;   // wave 64x64 sub-tile
  const int r16 = lane & 15, kg = lane >> 4;
  const int x7 = r16 & 7;

  f32x4 acc[4][4] = {};

  for (int t = 0; t < NT; ++t) {
    {
      char* da = (char*)Al + tid * 16;
      char* db = (char*)Bl + tid * 16;
      size_t ko = (size_t)t * 128;   // 64 elems * 2B
#pragma unroll
      for (int i = 0; i < 4; ++i) load_lds16(Ag + aoff[i] + ko, da + i * 4096);
#pragma unroll
      for (int i = 0; i < 4; ++i) load_lds16(Bg + boff[i] + ko, db + i * 4096);
    }
    __syncthreads();
    const char* Ap = (const char*)Al + (wr + r16) * 128;
    const char* Bp = (const char*)Bl + (wc + r16) * 128;
#pragma unroll
    for (int kf = 0; kf < 2; ++kf) {
      const int so = ((kf * 4 + kg) ^ x7) * 16;   // swizzled 16B-slot
      s16x8 a[4], b[4];
#pragma unroll
      for (int m = 0; m < 4; ++m) a[m] = *(const s16x8*)(Ap + m * 2048 + so);
#pragma unroll
      for (int n = 0; n < 4; ++n) b[n] = *(const s16x8*)(Bp + n * 2048 + so);
#pragma unroll
      for (int m = 0; m < 4; ++m)
#pragma unroll
        for (int n = 0; n < 4; ++n)
          acc[m][n] = __builtin_amdgcn_mfma_f32_16x16x32_bf16(a[m], b[n], acc[m][n], 0, 0, 0);
    }
    __syncthreads();
  }

  if constexpr (EPI == 1) {
#pragma unroll
    for (int m = 0; m < 4; ++m) {
      const int row_l = wr + m * 16 + kg * 4;
#pragma unroll
      for (int j = 0; j < 4; ++j) {
        size_t hrow = (size_t)(gbase + row_l + j) * FF + colT + wc;
#pragma unroll
        for (int n = 0; n < 4; ++n)
          Hout[hrow + n * 16 + r16] = f2bf(gelu_f(acc[m][n][j]));
      }
    }
  } else {
#pragma unroll
    for (int m = 0; m < 4; ++m) {
      const int row_l = wr + m * 16 + kg * 4;
#pragma unroll
      for (int j = 0; j < 4; ++j) {
        int r = row_start + row_l + j;
        if (r < ce) {
          int tok = idx_list[e * N_TOK + r];
          float g = gate_list[e * N_TOK + r];
          float* orow = Out + (size_t)tok * DIM + colT + wc;
#pragma unroll
          for (int n = 0; n < 4; ++n)
            atomicAdd(&orow[n * 16 + r16], acc[m][n][j] * g);
        }
      }
    }
  }
}

// ---------------- launch ----------------
extern "C" void kernel_launch(void* const* d_in, const int* in_sizes, int n_in,
                              void* d_out, int out_size, void* d_ws, size_t ws_size,
                              hipStream_t stream) {
  const float* x  = (const float*)d_in[0];
  const float* rw = (const float*)d_in[1];
  const float* w1 = (const float*)d_in[2];
  const float* w2 = (const float*)d_in[3];
  float* out = (float*)d_out;
  char* ws = (char*)d_ws;
  if (ws_size < NEED) return;
  const bool sep = ws_size >= NEED2;   // ws_size is fixed -> deterministic

  int*   counts    = (int*)(ws + OFF_COUNTS);
  int*   nt        = (int*)(ws + OFF_NT);
  int4*  t128      = (int4*)(ws + OFF_T128);
  int*   idx_list  = (int*)(ws + OFF_IDX);
  float* gate_list = (float*)(ws + OFF_GATE);
  unsigned short* xb  = (unsigned short*)(ws + OFF_XB);
  unsigned short* h   = (unsigned short*)(ws + OFF_H);
  unsigned short* wb  = (unsigned short*)(ws + OFF_WB);
  unsigned short* w2b = (unsigned short*)(ws + OFF_W2B);

  hipMemsetAsync(d_out, 0, (size_t)N_TOK * DIM * sizeof(float), stream);
  hipMemsetAsync(ws, 0, 256, stream);  // counts + nt

  const int n4 = NEXP * FF * DIM / 4;
  router_kernel<<<N_TOK / 4, 256, 0, stream>>>(x, rw, counts, idx_list, gate_list, xb);
  if (sep) {
    cvt2_f32_bf16<<<4096, 256, 0, stream>>>((const float4*)w1, (ushort4*)wb,
                                            (const float4*)w2, (ushort4*)w2b, n4);
  } else {
    cvt_f32_bf16<<<2048, 256, 0, stream>>>((const float4*)w1, (ushort4*)wb, n4);
  }
  schedule_kernel<<<1, 64, 0, stream>>>(counts, t128, nt);

  // GEMM1: grid 32 cx * 136 ty = 4352 (mult of 8); CPX = 4352/8 = 544
  moe_g<DIM, 1, 32, 544><<<32 * MAXT, 256, 0, stream>>>(
      xb, wb, h, nullptr, idx_list, gate_list, counts, t128, nt);
  if (!sep)
    cvt_f32_bf16<<<2048, 256, 0, stream>>>((const float4*)w2, (ushort4*)wb, n4);
  // GEMM2: grid 8 cx * 136 ty = 1088; CPX = 136
  moe_g<FF, 2, 8, 136><<<8 * MAXT, 256, 0, stream>>>(
      h, sep ? w2b : wb, nullptr, out, idx_list, gate_list, counts, t128, nt);
}

// Round 8
// 654.878 us; speedup vs baseline: 1.1146x; 1.0250x over previous
//
#include <hip/hip_runtime.h>
#include <hip/hip_bf16.h>
#include <stdint.h>

// ---------------- problem constants ----------------
#define N_TOK 8192
#define DIM   1024
#define FF    4096
#define NEXP  8
#define MAXT  136    // 128-row tiles: sum ceil(ce/128) <= 128+8; 136 = 8 XCDs * 17

// ---------------- workspace layout (bytes) ----------------
#define OFF_COUNTS 0ull
#define OFF_NT     64ull
#define OFF_T128   8192ull            // 136*16
#define OFF_IDX    16384ull           // 8*8192*4
#define OFF_GATE   278528ull
#define OFF_XB     1048576ull         // 8192*1024*2
#define OFF_H      17825792ull        // 17408*4096*2 fits in 150,994,944
#define OFF_WB     168820736ull       // 8*4096*1024*2 = 67,108,864 (w1b; w2b aliased if small ws)
#define OFF_W2B    235929600ull       // separate w2b when workspace permits
#define NEED       235929600ull
#define NEED2      303038464ull       // OFF_W2B + 67,108,864

typedef __attribute__((ext_vector_type(8))) short s16x8;   // 8 bf16 MFMA frag
typedef __attribute__((ext_vector_type(4))) float f32x4;   // MFMA accum

__device__ __forceinline__ unsigned short f2bf(float f) {
  union { float f; unsigned int u; } v; v.f = f;
  unsigned int u = v.u;
  unsigned int r = (u + 0x7FFFu + ((u >> 16) & 1u)) >> 16;  // RNE
  return (unsigned short)r;
}

// gelu: 0.5*x*(1+erf(x/sqrt2)), erf via A&S 7.1.26 (|err|<1.5e-7)
__device__ __forceinline__ float gelu_f(float x) {
  float s = x * 0.70710678118654752f;
  float a = fabsf(s);
  float t = 1.0f / fmaf(0.3275911f, a, 1.0f);
  float p = t * fmaf(t, fmaf(t, fmaf(t, fmaf(t, 1.061405429f, -1.453152027f),
                                     1.421413741f), -0.284496736f), 0.254829592f);
  float e = __expf(-a * a);
  float erf_a = 1.0f - p * e;
  float erf_s = (s >= 0.0f) ? erf_a : -erf_a;
  return 0.5f * x * (1.0f + erf_s);
}

// async global -> LDS, 16B per lane (dest = wave-uniform base + lane*16)
__device__ __forceinline__ void load_lds16(const void* g, void* l) {
  __builtin_amdgcn_global_load_lds(
      (const __attribute__((address_space(1))) unsigned int*)g,
      (__attribute__((address_space(3))) unsigned int*)l, 16, 0, 0);
}

// ---------------- f32 -> bf16 bulk converts ----------------
__global__ __launch_bounds__(256) void cvt_f32_bf16(const float4* __restrict__ in,
                                                    ushort4* __restrict__ out, int n4) {
  int i = blockIdx.x * 256 + threadIdx.x;
  int stride = gridDim.x * 256;
  for (; i < n4; i += stride) {
    float4 f = in[i];
    ushort4 u;
    u.x = f2bf(f.x); u.y = f2bf(f.y); u.z = f2bf(f.z); u.w = f2bf(f.w);
    out[i] = u;
  }
}

__global__ __launch_bounds__(256) void cvt2_f32_bf16(
    const float4* __restrict__ in1, ushort4* __restrict__ out1,
    const float4* __restrict__ in2, ushort4* __restrict__ out2, int n4) {
  int i = blockIdx.x * 256 + threadIdx.x;
  int stride = gridDim.x * 256;
  for (; i < 2 * n4; i += stride) {
    const float4* src = (i < n4) ? &in1[i] : &in2[i - n4];
    ushort4* dst = (i < n4) ? &out1[i] : &out2[i - n4];
    float4 f = *src;
    ushort4 u;
    u.x = f2bf(f.x); u.y = f2bf(f.y); u.z = f2bf(f.z); u.w = f2bf(f.w);
    *dst = u;
  }
}

// ---------------- router: 1 wave per token; also emits xb (bf16 copy of x) ----
__global__ __launch_bounds__(256) void router_kernel(
    const float* __restrict__ x, const float* __restrict__ rw,
    int* __restrict__ counts, int* __restrict__ idx_list, float* __restrict__ gate_list,
    unsigned short* __restrict__ xb) {
  int wid = threadIdx.x >> 6;
  int lane = threadIdx.x & 63;
  int token = blockIdx.x * 4 + wid;

  const float4* xr = (const float4*)(x + (size_t)token * DIM);
  ushort4* xw = (ushort4*)(xb + (size_t)token * DIM);
  float p[NEXP];
#pragma unroll
  for (int e = 0; e < NEXP; ++e) p[e] = 0.f;
#pragma unroll
  for (int c = 0; c < 4; ++c) {
    float4 xv = xr[c * 64 + lane];
    ushort4 u;
    u.x = f2bf(xv.x); u.y = f2bf(xv.y); u.z = f2bf(xv.z); u.w = f2bf(xv.w);
    xw[c * 64 + lane] = u;
#pragma unroll
    for (int e = 0; e < NEXP; ++e) {
      float4 wv = ((const float4*)(rw + (size_t)e * DIM))[c * 64 + lane];
      p[e] += xv.x * wv.x + xv.y * wv.y + xv.z * wv.z + xv.w * wv.w;
    }
  }
#pragma unroll
  for (int e = 0; e < NEXP; ++e) {
    float v = p[e];
#pragma unroll
    for (int off = 32; off > 0; off >>= 1) v += __shfl_xor(v, off, 64);
    p[e] = v;
  }
  if (lane == 0) {
    int e0 = 0; float v0 = p[0];
#pragma unroll
    for (int e = 1; e < NEXP; ++e) if (p[e] > v0) { v0 = p[e]; e0 = e; }
    int e1 = (e0 == 0) ? 1 : 0; float v1 = -3.4e38f;
#pragma unroll
    for (int e = 0; e < NEXP; ++e) if (e != e0 && p[e] > v1) { v1 = p[e]; e1 = e; }
    float ex = __expf(v1 - v0);
    float g0 = 1.0f / (1.0f + ex);
    float g1 = ex / (1.0f + ex);
    int p0 = atomicAdd(&counts[e0], 1);
    idx_list[e0 * N_TOK + p0] = token;
    gate_list[e0 * N_TOK + p0] = g0;
    int p1 = atomicAdd(&counts[e1], 1);
    idx_list[e1 * N_TOK + p1] = token;
    gate_list[e1 * N_TOK + p1] = g1;
  }
}

// ---------------- schedule: counts -> 128-row tile table (1 wave) ------------
__global__ void schedule_kernel(const int* __restrict__ counts, int4* __restrict__ t128,
                                int* __restrict__ nt) {
  int lane = threadIdx.x;
  int base[NEXP + 1], gb[NEXP];
  int b = 0, g = 0;
#pragma unroll
  for (int e = 0; e < NEXP; ++e) {
    base[e] = b; gb[e] = g;
    int n2 = (counts[e] + 127) >> 7;
    b += n2; g += n2 << 7;
  }
  base[NEXP] = b;
  if (lane == 0) nt[0] = b;
  for (int i = lane; i < b; i += 64) {
    int e = 0;
#pragma unroll
    for (int q = 0; q < NEXP - 1; ++q) if (i >= base[q + 1]) e = q + 1;
    int k = i - base[e];
    t128[i] = make_int4(e, k << 7, gb[e] + (k << 7), 0);
  }
}

// ---------------- grouped GEMM: 128x128, BK=64, 4 waves, single buffer -------
// r1/r7-skeleton (best measured per-structure): {stage; sync; ds_read+MFMA;
// sync} per K-tile; latency hidden by co-resident blocks (m114).
// L2-AWARE BLOCK MAPPING (this round's change): each XCD owns a contiguous
// ty-range of TPX=17 tiles (136 = 8*17). Within the XCD, blocks walk cx in
// CHUNKS of CW columns, ty-major inside a chunk, cx fastest:
//   xcd = o&7; r = o>>3; chunk = r/(TPX*CW); q = r%(TPX*CW);
//   ty = xcd*TPX + q/CW; cx = chunk*CW + q%CW.
// => resident B working set = CW col-panels (GEMM1: 2 MB) instead of the full
// 8 MB expert panel -> B stays in the XCD's 4 MiB L2 across all 17 ty instead
// of re-fetching from L3 per ty-row (the ~1 GB/XCD thrash behind the stuck
// ~10 TB/s stage rate). A-panels are re-read once per chunk (cheap).
// LDS conflict-free via source-pre-swizzled 16B-slot XOR (r3-verified, 0 conf).
// EPI==1: H[gbase+r] = gelu(A_gathered @ W^T) (bf16).
// EPI==2: atomicAdd(Out[token], gate * (H @ W^T)).
template <int KDIM, int EPI, int TPX, int CW>
__global__ __launch_bounds__(256, 4) void moe_g(
    const unsigned short* __restrict__ Abase, const unsigned short* __restrict__ Bb,
    unsigned short* __restrict__ Hout, float* __restrict__ Out,
    const int* __restrict__ idx_list, const float* __restrict__ gate_list,
    const int* __restrict__ counts, const int4* __restrict__ table,
    const int* __restrict__ n_tiles) {
  const int o = blockIdx.x;
  const int xcd = o & 7, r0 = o >> 3;
  const int chunk = r0 / (TPX * CW), q = r0 % (TPX * CW);
  const int ty = xcd * TPX + q / CW;
  const int cx = chunk * CW + q % CW;
  if (ty >= *n_tiles) return;
  int4 te = table[ty];
  const int e = te.x, row_start = te.y, gbase = te.z;
  const int ce = counts[e];
  const int tid = threadIdx.x;
  const int wid = tid >> 6, lane = tid & 63;
  const int colT = cx * 128;

  __shared__ unsigned short Al[128 * 64];
  __shared__ unsigned short Bl[128 * 64];

  // staging: thread -> rows {i*32+sr}, phys 16B-slot tid&7; source pre-swizzled
  const int sr = tid >> 3;
  const int scol = ((tid & 7) ^ (sr & 7)) * 8;
  size_t aoff[4], boff[4];
#pragma unroll
  for (int i = 0; i < 4; ++i) {
    int r = i * 32 + sr;
    if constexpr (EPI == 1) {
      int rl = row_start + r; if (rl >= ce) rl = ce - 1;   // clamp padded rows
      int tok = idx_list[e * N_TOK + rl];
      aoff[i] = ((size_t)tok * KDIM + scol) * 2;
    } else {
      aoff[i] = ((size_t)(gbase + r) * KDIM + scol) * 2;
    }
    boff[i] = ((size_t)e * FF * DIM + (size_t)(colT + r) * KDIM + scol) * 2;
  }
  const char* Ag = (const char*)Abase;
  const char* Bg = (const char*)Bb;
  const int NT = KDIM / 64;

  const int wr = (wid >> 1) * 64, wc = (wid & 1) * 64;   // wave 64x64 sub-tile
  const int r16 = lane & 15, kg = lane >> 4;
  const int x7 = r16 & 7;

  f32x4 acc[4][4] = {};

  for (int t = 0; t < NT; ++t) {
    {
      char* da = (char*)Al + tid * 16;
      char* db = (char*)Bl + tid * 16;
      size_t ko = (size_t)t * 128;   // 64 elems * 2B
#pragma unroll
      for (int i = 0; i < 4; ++i) load_lds16(Ag + aoff[i] + ko, da + i * 4096);
#pragma unroll
      for (int i = 0; i < 4; ++i) load_lds16(Bg + boff[i] + ko, db + i * 4096);
    }
    __syncthreads();
    const char* Ap = (const char*)Al + (wr + r16) * 128;
    const char* Bp = (const char*)Bl + (wc + r16) * 128;
#pragma unroll
    for (int kf = 0; kf < 2; ++kf) {
      const int so = ((kf * 4 + kg) ^ x7) * 16;   // swizzled 16B-slot
      s16x8 a[4], b[4];
#pragma unroll
      for (int m = 0; m < 4; ++m) a[m] = *(const s16x8*)(Ap + m * 2048 + so);
#pragma unroll
      for (int n = 0; n < 4; ++n) b[n] = *(const s16x8*)(Bp + n * 2048 + so);
#pragma unroll
      for (int m = 0; m < 4; ++m)
#pragma unroll
        for (int n = 0; n < 4; ++n)
          acc[m][n] = __builtin_amdgcn_mfma_f32_16x16x32_bf16(a[m], b[n], acc[m][n], 0, 0, 0);
    }
    __syncthreads();
  }

  if constexpr (EPI == 1) {
#pragma unroll
    for (int m = 0; m < 4; ++m) {
      const int row_l = wr + m * 16 + kg * 4;
#pragma unroll
      for (int j = 0; j < 4; ++j) {
        size_t hrow = (size_t)(gbase + row_l + j) * FF + colT + wc;
#pragma unroll
        for (int n = 0; n < 4; ++n)
          Hout[hrow + n * 16 + r16] = f2bf(gelu_f(acc[m][n][j]));
      }
    }
  } else {
#pragma unroll
    for (int m = 0; m < 4; ++m) {
      const int row_l = wr + m * 16 + kg * 4;
#pragma unroll
      for (int j = 0; j < 4; ++j) {
        int r = row_start + row_l + j;
        if (r < ce) {
          int tok = idx_list[e * N_TOK + r];
          float g = gate_list[e * N_TOK + r];
          float* orow = Out + (size_t)tok * DIM + colT + wc;
#pragma unroll
          for (int n = 0; n < 4; ++n)
            atomicAdd(&orow[n * 16 + r16], acc[m][n][j] * g);
        }
      }
    }
  }
}

// ---------------- launch ----------------
extern "C" void kernel_launch(void* const* d_in, const int* in_sizes, int n_in,
                              void* d_out, int out_size, void* d_ws, size_t ws_size,
                              hipStream_t stream) {
  const float* x  = (const float*)d_in[0];
  const float* rw = (const float*)d_in[1];
  const float* w1 = (const float*)d_in[2];
  const float* w2 = (const float*)d_in[3];
  float* out = (float*)d_out;
  char* ws = (char*)d_ws;
  if (ws_size < NEED) return;
  const bool sep = ws_size >= NEED2;   // ws_size is fixed -> deterministic

  int*   counts    = (int*)(ws + OFF_COUNTS);
  int*   nt        = (int*)(ws + OFF_NT);
  int4*  t128      = (int4*)(ws + OFF_T128);
  int*   idx_list  = (int*)(ws + OFF_IDX);
  float* gate_list = (float*)(ws + OFF_GATE);
  unsigned short* xb  = (unsigned short*)(ws + OFF_XB);
  unsigned short* h   = (unsigned short*)(ws + OFF_H);
  unsigned short* wb  = (unsigned short*)(ws + OFF_WB);
  unsigned short* w2b = (unsigned short*)(ws + OFF_W2B);

  hipMemsetAsync(d_out, 0, (size_t)N_TOK * DIM * sizeof(float), stream);
  hipMemsetAsync(ws, 0, 256, stream);  // counts + nt

  const int n4 = NEXP * FF * DIM / 4;
  router_kernel<<<N_TOK / 4, 256, 0, stream>>>(x, rw, counts, idx_list, gate_list, xb);
  if (sep) {
    cvt2_f32_bf16<<<4096, 256, 0, stream>>>((const float4*)w1, (ushort4*)wb,
                                            (const float4*)w2, (ushort4*)w2b, n4);
  } else {
    cvt_f32_bf16<<<2048, 256, 0, stream>>>((const float4*)w1, (ushort4*)wb, n4);
  }
  schedule_kernel<<<1, 64, 0, stream>>>(counts, t128, nt);

  // GEMM1: 32 cx * 136 ty = 4352 blocks; per XCD 544 = 4 chunks * (17 ty * 8 cx)
  moe_g<DIM, 1, 17, 8><<<32 * MAXT, 256, 0, stream>>>(
      xb, wb, h, nullptr, idx_list, gate_list, counts, t128, nt);
  if (!sep)
    cvt_f32_bf16<<<2048, 256, 0, stream>>>((const float4*)w2, (ushort4*)wb, n4);
  // GEMM2: 8 cx * 136 ty = 1088 blocks; per XCD 136 = 2 chunks * (17 ty * 4 cx)
  moe_g<FF, 2, 17, 4><<<8 * MAXT, 256, 0, stream>>>(
      h, sep ? w2b : wb, nullptr, out, idx_list, gate_list, counts, t128, nt);
}